// Round 9
// baseline (128.213 us; speedup 1.0000x reference)
//
#include <hip/hip_runtime.h>
#include <math.h>

// ---------------- constants ----------------
#define WS 11
#define PAD 10
#define NC 48            // 16 batch * 3 channels
#define C1V 1.0e-4f
#define C2V 9.0e-4f
#define PLROWS 42        // fixed row-conv plane: 32 outputs + 10 carry
#define RST 33           // float2 row stride (264B; odd -> 2-way max on b64)

struct Params { float g[WS]; };
struct ROff { int off[5]; int cnt[5]; float inv[5]; };
struct RowLoad { float4 a[4]; float4 b[4]; };   // 32 VGPRs of prefetched row data

// ---- issue the 8 global loads for one row-conv unit ----
__device__ __forceinline__ RowLoad row_load(
    const float* __restrict__ rowa, const float* __restrict__ rowb, const int xq[4])
{
    RowLoad L;
#pragma unroll
    for (int q = 0; q < 4; ++q) {
        L.a[q] = *(const float4*)(rowa + xq[q]);
        L.b[q] = *(const float4*)(rowb + xq[q]);
    }
    return L;
}

// ---- row-conv FMA: consume prefetched regs, write (s,d) and (s^2,d^2) planes ----
__device__ __forceinline__ void row_fma(
    const RowLoad& L, int cg,
    float2* __restrict__ rowSD, float2* __restrict__ rowE2, const Params& P)
{
    float m0[4]={0,0,0,0}, m1[4]={0,0,0,0}, m2[4]={0,0,0,0}, m3[4]={0,0,0,0};
#pragma unroll
    for (int q = 0; q < 4; ++q) {
        const float fa[4] = {L.a[q].x, L.a[q].y, L.a[q].z, L.a[q].w};
        const float fb[4] = {L.b[q].x, L.b[q].y, L.b[q].z, L.b[q].w};
#pragma unroll
        for (int e = 0; e < 4; ++e) {
            const int i = q * 4 + e;                 // window position 0..15
            const float s = fa[e] + fb[e], d = fa[e] - fb[e];
            const float ss = s * s, dd = d * d;
#pragma unroll
            for (int j = 0; j < 4; ++j) {
                const int k = i - j;
                if (k >= 0 && k < WS) {
                    const float g = P.g[k];
                    m0[j] += g * s;  m1[j] += g * d;
                    m2[j] += g * ss; m3[j] += g * dd;
                }
            }
        }
    }
#pragma unroll
    for (int j = 0; j < 4; ++j) {
        rowSD[cg*4 + j] = make_float2(m0[j], m1[j]);
        rowE2[cg*4 + j] = make_float2(m2[j], m3[j]);
    }
}

// ---------------- sliding-strip SSIM (+pool) kernel, software-pipelined ----
// Each block: 32-wide strip, CH chunks of 32 output rows. Fixed 42-row LDS
// planes + carry. Chunk t+1's global loads are issued right after the
// row-conv barrier and consumed after the next barrier -> latency hides
// under col-conv+SSIM compute. grid: (tilesX*tilesY, NC); block: 256.
template<int CH, int POOL>
__global__ __launch_bounds__(256, 4) void ssim_strip_kernel(
    const float* __restrict__ img1, const float* __restrict__ img2,
    float* __restrict__ pool1, float* __restrict__ pool2,
    int H, int OH, int tilesX, Params P,
    float2* __restrict__ partial, int partial_off)
{
    __shared__ float2 rpSD[PLROWS][RST];   // (ms, md)
    __shared__ float2 rpE2[PLROWS][RST];   // (Es2, Ed2)
    __shared__ float reds[4], redc[4];
    const int tid   = threadIdx.x;
    const int tileX = blockIdx.x % tilesX;
    const int ty    = blockIdx.x / tilesX;
    const int img   = blockIdx.y;
    const size_t ib = (size_t)img * H * H;
    const float* __restrict__ p1 = img1 + ib;
    const float* __restrict__ p2 = img2 + ib;
    const int ox0 = tileX * 32;
    const int oy0 = ty * (CH * 32);

    // fixed per-thread roles
    const int r_unit = tid >> 3;          // 0..31: row-conv row within chunk
    const int cg     = tid & 7;           // row-conv col group
    int xq[4];                            // clamped, constant across all rows
#pragma unroll
    for (int q = 0; q < 4; ++q) xq[q] = min(ox0 + cg*4 + q*4, H - 4);

    const int cc  = tid & 31;             // col-conv column
    const int r0c = (tid >> 5) * 4;       // col-conv first row in chunk
    const int px  = tid & 15, py = tid >> 4;   // pool roles

    // prefetch chunk 0's row-conv loads (all threads)
    RowLoad L;
    {
        const int y = min(oy0 + 10 + r_unit, H - 1);
        L = row_load(p1 + (size_t)y*H, p2 + (size_t)y*H, xq);
    }

    // preload strip rows 0..9 -> slots 0..9 (one-time, 80 threads)
    if (tid < 80) {
        const int y = min(oy0 + r_unit, H - 1);
        RowLoad Lp = row_load(p1 + (size_t)y*H, p2 + (size_t)y*H, xq);
        row_fma(Lp, cg, &rpSD[r_unit][0], &rpE2[r_unit][0], P);
    }

    float ssim_acc = 0.f, cs_acc = 0.f;

    for (int t = 0; t < CH; ++t) {
        // ---- row conv FMA from prefetched regs -> slots 10..41 ----
        row_fma(L, cg, &rpSD[10 + r_unit][0], &rpE2[10 + r_unit][0], P);
        __syncthreads();

        // ---- issue next chunk's loads NOW (hide under col-conv) ----
        if (t + 1 < CH) {
            const int y = min(oy0 + (t+1)*32 + 10 + r_unit, H - 1);
            L = row_load(p1 + (size_t)y*H, p2 + (size_t)y*H, xq);
        }
        // ---- issue this chunk's pool loads too ----
        float2 a0, a1, b0, b1;
        if (POOL) {
            const int yy = oy0 + t*32 + 2*py;
            const int xx = ox0 + 2*px;
            a0 = *(const float2*)(p1 + (size_t)yy*H + xx);
            a1 = *(const float2*)(p1 + (size_t)(yy+1)*H + xx);
            b0 = *(const float2*)(p2 + (size_t)yy*H + xx);
            b1 = *(const float2*)(p2 + (size_t)(yy+1)*H + xx);
        }

        // ---- col conv + SSIM: 4 consecutive rows per thread ----
        float A0[4]={0,0,0,0}, A1[4]={0,0,0,0}, A2[4]={0,0,0,0}, A3[4]={0,0,0,0};
#pragma unroll
        for (int k = 0; k < 14; ++k) {
            const float2 vsd = rpSD[r0c + k][cc];   // base + k*264B immediate
            const float2 ve2 = rpE2[r0c + k][cc];
#pragma unroll
            for (int j = 0; j < 4; ++j) {
                const int tt = k - j;
                if (tt >= 0 && tt < WS) {
                    const float g = P.g[tt];
                    A0[j]+=g*vsd.x; A1[j]+=g*vsd.y; A2[j]+=g*ve2.x; A3[j]+=g*ve2.y;
                }
            }
        }
        const int ox = ox0 + cc;
#pragma unroll
        for (int j = 0; j < 4; ++j) {
            const int oy = oy0 + t*32 + r0c + j;
            if (oy < OH && ox < OH) {     // OW == OH (square)
                const float ms = A0[j], md = A1[j], Es = A2[j], Ed = A3[j];
                const float ms2 = ms*ms, md2 = md*md;
                const float mu12 = 0.25f * (ms2 - md2);
                const float musq = 0.5f  * (ms2 + md2);             // mu1^2+mu2^2
                const float v1 = 0.5f * (Es - Ed) - 2.f*mu12 + C2V; // 2*sig12+C2
                const float v2 = 0.5f * (Es + Ed) - musq + C2V;     // sig1+sig2+C2
                const float rv2 = __builtin_amdgcn_rcpf(v2);
                const float cs  = v1 * rv2;
                const float ssim = (2.f*mu12 + C1V) *
                                   __builtin_amdgcn_rcpf(musq + C1V) * cs;
                ssim_acc += ssim;
                cs_acc   += cs;
            }
        }

        // ---- pool compute + store (loads issued above, long since landed) ----
        if (POOL) {
            const int h = H >> 1;
            const size_t ob = (size_t)img*h*h +
                              (size_t)(((oy0 + t*32) >> 1) + py)*h + (ox0 >> 1) + px;
            pool1[ob] = 0.25f * (a0.x + a0.y + a1.x + a1.y);
            pool2[ob] = 0.25f * (b0.x + b0.y + b1.x + b1.y);
        }

        // ---- carry: slots 32..41 -> slots 0..9 (10 rows x 32 cols, 2 planes)
        if (t + 1 < CH) {
            __syncthreads();              // col-conv reads of slots 0..9 done
            for (int u = tid; u < 320; u += 256) {
                const int r = u >> 5, c = u & 31;
                rpSD[r][c] = rpSD[32 + r][c];
                rpE2[r][c] = rpE2[32 + r][c];
            }
            __syncthreads();              // carry done before next row-conv
        }
    }

    // ---- deterministic block reduction -> one partial per block ----
#pragma unroll
    for (int off = 32; off > 0; off >>= 1) {
        ssim_acc += __shfl_down(ssim_acc, off);
        cs_acc   += __shfl_down(cs_acc, off);
    }
    const int wave = tid >> 6, lane = tid & 63;
    if (lane == 0) { reds[wave] = ssim_acc; redc[wave] = cs_acc; }
    __syncthreads();
    if (tid == 0) {
        const float s   = reds[0] + reds[1] + reds[2] + reds[3];
        const float cc2 = redc[0] + redc[1] + redc[2] + redc[3];
        partial[(size_t)partial_off + (size_t)blockIdx.y * gridDim.x + blockIdx.x] =
            make_float2(s, cc2);
    }
}

// ---------------- single fused reduce over all levels + final product ----------------
__global__ __launch_bounds__(256) void reduce_final_kernel(
    const float2* __restrict__ partial, ROff ro, float* __restrict__ out)
{
    __shared__ float sS[5], sC[5];
    __shared__ float reds[4], redc[4];
    const int tid = threadIdx.x;
    for (int l = 0; l < 5; ++l) {
        float s = 0.f, c = 0.f;
        for (int i = tid; i < ro.cnt[l]; i += 256) {
            const float2 v = partial[ro.off[l] + i];
            s += v.x; c += v.y;
        }
#pragma unroll
        for (int off = 32; off > 0; off >>= 1) {
            s += __shfl_down(s, off);
            c += __shfl_down(c, off);
        }
        const int wave = tid >> 6, lane = tid & 63;
        if (lane == 0) { reds[wave] = s; redc[wave] = c; }
        __syncthreads();
        if (tid == 0) {
            sS[l] = (reds[0] + reds[1] + reds[2] + reds[3]) * ro.inv[l];
            sC[l] = (redc[0] + redc[1] + redc[2] + redc[3]) * ro.inv[l];
        }
        __syncthreads();
    }
    if (tid == 0) {
        const float w[5] = {0.0448f, 0.2856f, 0.3001f, 0.2363f, 0.1333f};
        float prod = 1.f;
#pragma unroll
        for (int i = 0; i < 4; ++i)
            prod *= powf((sC[i] + 1.f) * 0.5f, w[i]);
        prod *= powf((sS[4] + 1.f) * 0.5f, w[4]);
        out[0] = prod;
    }
}

// ---------------- host launch ----------------
extern "C" void kernel_launch(void* const* d_in, const int* in_sizes, int n_in,
                              void* d_out, int out_size, void* d_ws, size_t ws_size,
                              hipStream_t stream)
{
    const float* img1 = (const float*)d_in[0];
    const float* img2 = (const float*)d_in[1];
    float* out = (float*)d_out;
    float* ws  = (float*)d_ws;

    // Gaussian window (sigma = 1.5), normalized
    Params P;
    {
        double g[WS], sum = 0.0;
        for (int i = 0; i < WS; ++i) {
            double x = (double)i - (WS / 2);
            g[i] = exp(-x * x / (2.0 * 1.5 * 1.5));
            sum += g[i];
        }
        for (int i = 0; i < WS; ++i) P.g[i] = (float)(g[i] / sum);
    }

    // workspace layout: pyramid levels 1..4 (both images), then partials
    float* p1[5]; float* p2[5];
    p1[0] = (float*)img1; p2[0] = (float*)img2;
    size_t o = 0;
    for (int l = 1; l < 5; ++l) {
        const int H = 512 >> l;
        p1[l] = ws + o; o += (size_t)NC * H * H;
        p2[l] = ws + o; o += (size_t)NC * H * H;
    }
    float2* partial = (float2*)(ws + o);
    (void)ws_size; (void)in_sizes; (void)n_in; (void)out_size;

    const int CHv[5] = {4, 2, 1, 1, 1};   // chunks per strip, per level
    ROff ro;
    {
        int off = 0;
        for (int l = 0; l < 5; ++l) {
            const int H = 512 >> l, OH = H - PAD;
            const int tilesX = (OH + 31) / 32;
            const int tilesY = (OH + CHv[l]*32 - 1) / (CHv[l]*32);
            ro.off[l] = off;
            ro.cnt[l] = tilesX * tilesY * NC;
            ro.inv[l] = 1.f / ((float)NC * OH * OH);
            off += ro.cnt[l];
        }
    }

    for (int l = 0; l < 5; ++l) {
        const int H = 512 >> l, OH = H - PAD;
        const int tilesX = (OH + 31) / 32;
        const int tilesY = (OH + CHv[l]*32 - 1) / (CHv[l]*32);
        const dim3 grid(tilesX * tilesY, NC);
        switch (l) {
        case 0:
            ssim_strip_kernel<4,1><<<grid, 256, 0, stream>>>(
                p1[0], p2[0], p1[1], p2[1], H, OH, tilesX, P, partial, ro.off[0]);
            break;
        case 1:
            ssim_strip_kernel<2,1><<<grid, 256, 0, stream>>>(
                p1[1], p2[1], p1[2], p2[2], H, OH, tilesX, P, partial, ro.off[1]);
            break;
        case 2:
            ssim_strip_kernel<1,1><<<grid, 256, 0, stream>>>(
                p1[2], p2[2], p1[3], p2[3], H, OH, tilesX, P, partial, ro.off[2]);
            break;
        case 3:
            ssim_strip_kernel<1,1><<<grid, 256, 0, stream>>>(
                p1[3], p2[3], p1[4], p2[4], H, OH, tilesX, P, partial, ro.off[3]);
            break;
        default:
            ssim_strip_kernel<1,0><<<grid, 256, 0, stream>>>(
                p1[4], p2[4], nullptr, nullptr, H, OH, tilesX, P, partial, ro.off[4]);
            break;
        }
    }

    reduce_final_kernel<<<1, 256, 0, stream>>>(partial, ro, out);
}

// Round 10
// 106.248 us; speedup vs baseline: 1.2067x; 1.2067x over previous
//
#include <hip/hip_runtime.h>
#include <math.h>

// ---------------- constants ----------------
#define WS 11
#define PAD 10
#define NC 48            // 16 batch * 3 channels
#define C1V 1.0e-4f
#define C2V 9.0e-4f
#define PLROWS 42        // fixed row-conv plane: 32 outputs + 10 carry
#define RST 33           // float2 row stride (264B)

struct Params { float g[WS]; };
struct ROff { int off[5]; int cnt[5]; float inv[5]; };
struct RowLoad { float4 a[4]; float4 b[4]; };   // 32 VGPRs of prefetched row data

// ---- issue the 8 global loads for one row-conv unit ----
__device__ __forceinline__ RowLoad row_load(
    const float* __restrict__ rowa, const float* __restrict__ rowb, const int xq[4])
{
    RowLoad L;
#pragma unroll
    for (int q = 0; q < 4; ++q) {
        L.a[q] = *(const float4*)(rowa + xq[q]);
        L.b[q] = *(const float4*)(rowb + xq[q]);
    }
    return L;
}

// ---- row-conv FMA: consume prefetched regs, write (s,d) and (s^2,d^2) planes ----
__device__ __forceinline__ void row_fma(
    const RowLoad& L, int cg,
    float2* __restrict__ rowSD, float2* __restrict__ rowE2, const Params& P)
{
    float m0[4]={0,0,0,0}, m1[4]={0,0,0,0}, m2[4]={0,0,0,0}, m3[4]={0,0,0,0};
#pragma unroll
    for (int q = 0; q < 4; ++q) {
        const float fa[4] = {L.a[q].x, L.a[q].y, L.a[q].z, L.a[q].w};
        const float fb[4] = {L.b[q].x, L.b[q].y, L.b[q].z, L.b[q].w};
#pragma unroll
        for (int e = 0; e < 4; ++e) {
            const int i = q * 4 + e;                 // window position 0..15
            const float s = fa[e] + fb[e], d = fa[e] - fb[e];
            const float ss = s * s, dd = d * d;
#pragma unroll
            for (int j = 0; j < 4; ++j) {
                const int k = i - j;
                if (k >= 0 && k < WS) {
                    const float g = P.g[k];
                    m0[j] += g * s;  m1[j] += g * d;
                    m2[j] += g * ss; m3[j] += g * dd;
                }
            }
        }
    }
#pragma unroll
    for (int j = 0; j < 4; ++j) {
        rowSD[cg*4 + j] = make_float2(m0[j], m1[j]);
        rowE2[cg*4 + j] = make_float2(m2[j], m3[j]);
    }
}

// ---------------- sliding-strip SSIM (+pool), double-buffered planes ----------
// ONE barrier per chunk: row_fma(t) writes buf[cur] rows 10..41; barrier; then
// carry copies buf[cur] rows 32..41 -> buf[nxt] rows 0..9 (reads protected by
// the barrier, writes go to the idle buffer) while col-conv reads buf[cur];
// next chunk's row_fma writes buf[nxt] rows 10..41 (disjoint) with no barrier.
// Chunk loop fully unrolled -> all LDS indices are immediates.
// NO min-waves launch-bounds hint: R9 showed the allocator spills the 32-reg
// prefetch tile under a waves-per-EU budget (VGPR=64 + 80MB scratch traffic).
template<int CH, int POOL>
__global__ __launch_bounds__(256) void ssim_strip_kernel(
    const float* __restrict__ img1, const float* __restrict__ img2,
    float* __restrict__ pool1, float* __restrict__ pool2,
    int H, int OH, int tilesX, Params P,
    float2* __restrict__ partial, int partial_off)
{
    __shared__ float2 rpSD[2][PLROWS][RST];   // (ms, md)
    __shared__ float2 rpE2[2][PLROWS][RST];   // (Es2, Ed2)
    __shared__ float reds[4], redc[4];
    const int tid   = threadIdx.x;
    const int tileX = blockIdx.x % tilesX;
    const int ty    = blockIdx.x / tilesX;
    const int img   = blockIdx.y;
    const size_t ib = (size_t)img * H * H;
    const float* __restrict__ p1 = img1 + ib;
    const float* __restrict__ p2 = img2 + ib;
    const int ox0 = tileX * 32;
    const int oy0 = ty * (CH * 32);

    // fixed per-thread roles
    const int r_unit = tid >> 3;          // 0..31: row-conv row within chunk
    const int cg     = tid & 7;           // row-conv col group
    int xq[4];                            // clamped, constant across all rows
#pragma unroll
    for (int q = 0; q < 4; ++q) xq[q] = min(ox0 + cg*4 + q*4, H - 4);

    const int cc  = tid & 31;             // col-conv column
    const int r0c = (tid >> 5) * 4;       // col-conv first row in chunk
    const int px  = tid & 15, py = tid >> 4;   // pool roles

    // prefetch chunk 0's row-conv loads (all threads)
    RowLoad L;
    {
        const int y = min(oy0 + 10 + r_unit, H - 1);
        L = row_load(p1 + (size_t)y*H, p2 + (size_t)y*H, xq);
    }
    // preload strip rows 0..9 -> buf0 slots 0..9 (disjoint from row_fma's 10..41)
    if (tid < 80) {
        const int y = min(oy0 + r_unit, H - 1);
        RowLoad Lp = row_load(p1 + (size_t)y*H, p2 + (size_t)y*H, xq);
        row_fma(Lp, cg, &rpSD[0][r_unit][0], &rpE2[0][r_unit][0], P);
    }

    float ssim_acc = 0.f, cs_acc = 0.f;

#pragma unroll
    for (int t = 0; t < CH; ++t) {
        const int cur = t & 1, nxt = cur ^ 1;

        // ---- row conv FMA from prefetched regs -> buf[cur] slots 10..41 ----
        row_fma(L, cg, &rpSD[cur][10 + r_unit][0], &rpE2[cur][10 + r_unit][0], P);
        __syncthreads();   // the ONLY barrier per chunk

        // ---- issue next chunk's loads NOW (consumed before next barrier) ----
        if (t + 1 < CH) {
            const int y = min(oy0 + (t+1)*32 + 10 + r_unit, H - 1);
            L = row_load(p1 + (size_t)y*H, p2 + (size_t)y*H, xq);
        }
        // ---- issue this chunk's pool loads too ----
        float2 a0, a1, b0, b1;
        if (POOL) {
            const int yy = oy0 + t*32 + 2*py;
            const int xx = ox0 + 2*px;
            a0 = *(const float2*)(p1 + (size_t)yy*H + xx);
            a1 = *(const float2*)(p1 + (size_t)(yy+1)*H + xx);
            b0 = *(const float2*)(p2 + (size_t)yy*H + xx);
            b1 = *(const float2*)(p2 + (size_t)(yy+1)*H + xx);
        }

        // ---- col conv + SSIM: 4 consecutive rows per thread, from buf[cur] ----
        float A0[4]={0,0,0,0}, A1[4]={0,0,0,0}, A2[4]={0,0,0,0}, A3[4]={0,0,0,0};
#pragma unroll
        for (int k = 0; k < 14; ++k) {
            const float2 vsd = rpSD[cur][r0c + k][cc];   // immediate offsets
            const float2 ve2 = rpE2[cur][r0c + k][cc];
#pragma unroll
            for (int j = 0; j < 4; ++j) {
                const int tt = k - j;
                if (tt >= 0 && tt < WS) {
                    const float g = P.g[tt];
                    A0[j]+=g*vsd.x; A1[j]+=g*vsd.y; A2[j]+=g*ve2.x; A3[j]+=g*ve2.y;
                }
            }
        }
        const int ox = ox0 + cc;
#pragma unroll
        for (int j = 0; j < 4; ++j) {
            const int oy = oy0 + t*32 + r0c + j;
            if (oy < OH && ox < OH) {     // OW == OH (square)
                const float ms = A0[j], md = A1[j], Es = A2[j], Ed = A3[j];
                const float ms2 = ms*ms, md2 = md*md;
                const float mu12 = 0.25f * (ms2 - md2);
                const float musq = 0.5f  * (ms2 + md2);             // mu1^2+mu2^2
                const float v1 = 0.5f * (Es - Ed) - 2.f*mu12 + C2V; // 2*sig12+C2
                const float v2 = 0.5f * (Es + Ed) - musq + C2V;     // sig1+sig2+C2
                const float rv2 = __builtin_amdgcn_rcpf(v2);
                const float cs  = v1 * rv2;
                const float ssim = (2.f*mu12 + C1V) *
                                   __builtin_amdgcn_rcpf(musq + C1V) * cs;
                ssim_acc += ssim;
                cs_acc   += cs;
            }
        }

        // ---- pool compute + store ----
        if (POOL) {
            const int h = H >> 1;
            const size_t ob = (size_t)img*h*h +
                              (size_t)(((oy0 + t*32) >> 1) + py)*h + (ox0 >> 1) + px;
            pool1[ob] = 0.25f * (a0.x + a0.y + a1.x + a1.y);
            pool2[ob] = 0.25f * (b0.x + b0.y + b1.x + b1.y);
        }

        // ---- carry into the idle buffer (no barrier needed around it):
        // reads buf[cur] rows 32..41 (protected by this chunk's barrier),
        // writes buf[nxt] rows 0..9 (next row_fma writes rows 10..41, disjoint;
        // next col-conv reads them only after the next barrier).
        if (t + 1 < CH) {
            for (int u = tid; u < 320; u += 256) {
                const int r = u >> 5, c = u & 31;
                rpSD[nxt][r][c] = rpSD[cur][32 + r][c];
                rpE2[nxt][r][c] = rpE2[cur][32 + r][c];
            }
        }
    }

    // ---- deterministic block reduction -> one partial per block ----
#pragma unroll
    for (int off = 32; off > 0; off >>= 1) {
        ssim_acc += __shfl_down(ssim_acc, off);
        cs_acc   += __shfl_down(cs_acc, off);
    }
    const int wave = tid >> 6, lane = tid & 63;
    if (lane == 0) { reds[wave] = ssim_acc; redc[wave] = cs_acc; }
    __syncthreads();
    if (tid == 0) {
        const float s   = reds[0] + reds[1] + reds[2] + reds[3];
        const float cc2 = redc[0] + redc[1] + redc[2] + redc[3];
        partial[(size_t)partial_off + (size_t)blockIdx.y * gridDim.x + blockIdx.x] =
            make_float2(s, cc2);
    }
}

// ---------------- single fused reduce over all levels + final product ----------------
__global__ __launch_bounds__(256) void reduce_final_kernel(
    const float2* __restrict__ partial, ROff ro, float* __restrict__ out)
{
    __shared__ float sS[5], sC[5];
    __shared__ float reds[4], redc[4];
    const int tid = threadIdx.x;
    for (int l = 0; l < 5; ++l) {
        float s = 0.f, c = 0.f;
        for (int i = tid; i < ro.cnt[l]; i += 256) {
            const float2 v = partial[ro.off[l] + i];
            s += v.x; c += v.y;
        }
#pragma unroll
        for (int off = 32; off > 0; off >>= 1) {
            s += __shfl_down(s, off);
            c += __shfl_down(c, off);
        }
        const int wave = tid >> 6, lane = tid & 63;
        if (lane == 0) { reds[wave] = s; redc[wave] = c; }
        __syncthreads();
        if (tid == 0) {
            sS[l] = (reds[0] + reds[1] + reds[2] + reds[3]) * ro.inv[l];
            sC[l] = (redc[0] + redc[1] + redc[2] + redc[3]) * ro.inv[l];
        }
        __syncthreads();
    }
    if (tid == 0) {
        const float w[5] = {0.0448f, 0.2856f, 0.3001f, 0.2363f, 0.1333f};
        float prod = 1.f;
#pragma unroll
        for (int i = 0; i < 4; ++i)
            prod *= powf((sC[i] + 1.f) * 0.5f, w[i]);
        prod *= powf((sS[4] + 1.f) * 0.5f, w[4]);
        out[0] = prod;
    }
}

// ---------------- host launch ----------------
extern "C" void kernel_launch(void* const* d_in, const int* in_sizes, int n_in,
                              void* d_out, int out_size, void* d_ws, size_t ws_size,
                              hipStream_t stream)
{
    const float* img1 = (const float*)d_in[0];
    const float* img2 = (const float*)d_in[1];
    float* out = (float*)d_out;
    float* ws  = (float*)d_ws;

    // Gaussian window (sigma = 1.5), normalized
    Params P;
    {
        double g[WS], sum = 0.0;
        for (int i = 0; i < WS; ++i) {
            double x = (double)i - (WS / 2);
            g[i] = exp(-x * x / (2.0 * 1.5 * 1.5));
            sum += g[i];
        }
        for (int i = 0; i < WS; ++i) P.g[i] = (float)(g[i] / sum);
    }

    // workspace layout: pyramid levels 1..4 (both images), then partials
    float* p1[5]; float* p2[5];
    p1[0] = (float*)img1; p2[0] = (float*)img2;
    size_t o = 0;
    for (int l = 1; l < 5; ++l) {
        const int H = 512 >> l;
        p1[l] = ws + o; o += (size_t)NC * H * H;
        p2[l] = ws + o; o += (size_t)NC * H * H;
    }
    float2* partial = (float2*)(ws + o);
    (void)ws_size; (void)in_sizes; (void)n_in; (void)out_size;

    const int CHv[5] = {4, 2, 1, 1, 1};   // chunks per strip, per level
    ROff ro;
    {
        int off = 0;
        for (int l = 0; l < 5; ++l) {
            const int H = 512 >> l, OH = H - PAD;
            const int tilesX = (OH + 31) / 32;
            const int tilesY = (OH + CHv[l]*32 - 1) / (CHv[l]*32);
            ro.off[l] = off;
            ro.cnt[l] = tilesX * tilesY * NC;
            ro.inv[l] = 1.f / ((float)NC * OH * OH);
            off += ro.cnt[l];
        }
    }

    for (int l = 0; l < 5; ++l) {
        const int H = 512 >> l, OH = H - PAD;
        const int tilesX = (OH + 31) / 32;
        const int tilesY = (OH + CHv[l]*32 - 1) / (CHv[l]*32);
        const dim3 grid(tilesX * tilesY, NC);
        switch (l) {
        case 0:
            ssim_strip_kernel<4,1><<<grid, 256, 0, stream>>>(
                p1[0], p2[0], p1[1], p2[1], H, OH, tilesX, P, partial, ro.off[0]);
            break;
        case 1:
            ssim_strip_kernel<2,1><<<grid, 256, 0, stream>>>(
                p1[1], p2[1], p1[2], p2[2], H, OH, tilesX, P, partial, ro.off[1]);
            break;
        case 2:
            ssim_strip_kernel<1,1><<<grid, 256, 0, stream>>>(
                p1[2], p2[2], p1[3], p2[3], H, OH, tilesX, P, partial, ro.off[2]);
            break;
        case 3:
            ssim_strip_kernel<1,1><<<grid, 256, 0, stream>>>(
                p1[3], p2[3], p1[4], p2[4], H, OH, tilesX, P, partial, ro.off[3]);
            break;
        default:
            ssim_strip_kernel<1,0><<<grid, 256, 0, stream>>>(
                p1[4], p2[4], nullptr, nullptr, H, OH, tilesX, P, partial, ro.off[4]);
            break;
        }
    }

    reduce_final_kernel<<<1, 256, 0, stream>>>(partial, ro, out);
}

// Round 11
// 101.722 us; speedup vs baseline: 1.2604x; 1.0445x over previous
//
#include <hip/hip_runtime.h>
#include <math.h>

// ---------------- constants ----------------
#define WS 11
#define PAD 10
#define NC 48            // 16 batch * 3 channels
#define C1V 1.0e-4f
#define C2V 9.0e-4f
#define PLROWS 42        // fixed row-conv plane: 32 outputs + 10 carry
#define RST 33           // v2f row stride (264B; odd -> 2-way max on b64)

// packed fp32 pair -> clang emits v_pk_fma_f32 (VOP3P) on gfx950
typedef float v2f __attribute__((ext_vector_type(2)));

struct Params { float g[WS]; };
struct ROff { int off[5]; int cnt[5]; float inv[5]; };

// ---- one row-conv unit: 4 output cols, packed channels (s,d) / (s^2,d^2) ----
__device__ __forceinline__ void row_conv_unit(
    const float* __restrict__ rowa, const float* __restrict__ rowb,
    const int xq[4], int cg,
    v2f* __restrict__ rowSD, v2f* __restrict__ rowE2, const Params& P)
{
    v2f msd[4] = {{0,0},{0,0},{0,0},{0,0}};
    v2f me2[4] = {{0,0},{0,0},{0,0},{0,0}};
#pragma unroll
    for (int q = 0; q < 4; ++q) {
        const float4 va = *(const float4*)(rowa + xq[q]);
        const float4 vb = *(const float4*)(rowb + xq[q]);
        const float fa[4] = {va.x, va.y, va.z, va.w};
        const float fb[4] = {vb.x, vb.y, vb.z, vb.w};
#pragma unroll
        for (int e = 0; e < 4; ++e) {
            const int i = q * 4 + e;                 // window position 0..15
            v2f sd; sd.x = fa[e] + fb[e]; sd.y = fa[e] - fb[e];
            const v2f sq = sd * sd;                  // v_pk_mul_f32
#pragma unroll
            for (int j = 0; j < 4; ++j) {
                const int k = i - j;
                if (k >= 0 && k < WS) {
                    const float g = P.g[k];
                    msd[j] += g * sd;                // v_pk_fma_f32
                    me2[j] += g * sq;                // v_pk_fma_f32
                }
            }
        }
    }
#pragma unroll
    for (int j = 0; j < 4; ++j) {
        rowSD[cg*4 + j] = msd[j];
        rowE2[cg*4 + j] = me2[j];
    }
}

// ---------------- sliding-strip SSIM (+pool) kernel ----------------
// R8 base structure (single 42-row plane + carry, 2-3 barriers/chunk) +
// packed-f32 math + half-batched col-conv LDS reads (7 rows x 2 planes into
// 28 VGPRs, reads pipeline instead of one-latency-per-k).
// NO min-waves launch-bounds hint (R9: a hint-derived VGPR cap = spill storm).
template<int CH, int POOL>
__global__ __launch_bounds__(256) void ssim_strip_kernel(
    const float* __restrict__ img1, const float* __restrict__ img2,
    float* __restrict__ pool1, float* __restrict__ pool2,
    int H, int OH, int tilesX, Params P,
    float2* __restrict__ partial, int partial_off)
{
    __shared__ v2f rpSD[PLROWS][RST];   // (ms, md)
    __shared__ v2f rpE2[PLROWS][RST];   // (Es2, Ed2)
    __shared__ float reds[4], redc[4];
    const int tid   = threadIdx.x;
    const int tileX = blockIdx.x % tilesX;
    const int ty    = blockIdx.x / tilesX;
    const int img   = blockIdx.y;
    const size_t ib = (size_t)img * H * H;
    const float* __restrict__ p1 = img1 + ib;
    const float* __restrict__ p2 = img2 + ib;
    const int ox0 = tileX * 32;
    const int oy0 = ty * (CH * 32);

    // fixed per-thread roles
    const int r_unit = tid >> 3;          // 0..31: row-conv row within chunk
    const int cg     = tid & 7;           // row-conv col group
    int xq[4];                            // clamped, constant across all rows
#pragma unroll
    for (int q = 0; q < 4; ++q) xq[q] = min(ox0 + cg*4 + q*4, H - 4);

    const int cc  = tid & 31;             // col-conv column
    const int r0c = (tid >> 5) * 4;       // col-conv first row in chunk

    // preload strip rows 0..9 -> slots 0..9
    if (tid < 80) {
        const int y = min(oy0 + r_unit, H - 1);
        row_conv_unit(p1 + (size_t)y*H, p2 + (size_t)y*H, xq, cg,
                      &rpSD[r_unit][0], &rpE2[r_unit][0], P);
    }

    float ssim_acc = 0.f, cs_acc = 0.f;

    for (int t = 0; t < CH; ++t) {
        // ---- row conv: rows t*32+10 .. t*32+41 -> slots 10..41 (1/thread) ----
        {
            const int y = min(oy0 + t*32 + 10 + r_unit, H - 1);
            row_conv_unit(p1 + (size_t)y*H, p2 + (size_t)y*H, xq, cg,
                          &rpSD[10 + r_unit][0], &rpE2[10 + r_unit][0], P);
        }
        __syncthreads();

        // ---- col conv, half-batched reads + packed FMA ----
        v2f Asd[4] = {{0,0},{0,0},{0,0},{0,0}};
        v2f Ae2[4] = {{0,0},{0,0},{0,0},{0,0}};
        {
            v2f bsd[7], be2[7];
#pragma unroll
            for (int k = 0; k < 7; ++k) {            // batch 1: rows r0c..r0c+6
                bsd[k] = rpSD[r0c + k][cc];
                be2[k] = rpE2[r0c + k][cc];
            }
#pragma unroll
            for (int k = 0; k < 7; ++k) {
#pragma unroll
                for (int j = 0; j < 4; ++j) {
                    const int tt = k - j;
                    if (tt >= 0 && tt < WS) {
                        const float g = P.g[tt];
                        Asd[j] += g * bsd[k];
                        Ae2[j] += g * be2[k];
                    }
                }
            }
#pragma unroll
            for (int k = 7; k < 14; ++k) {           // batch 2: rows r0c+7..r0c+13
                bsd[k-7] = rpSD[r0c + k][cc];
                be2[k-7] = rpE2[r0c + k][cc];
            }
#pragma unroll
            for (int k = 7; k < 14; ++k) {
#pragma unroll
                for (int j = 0; j < 4; ++j) {
                    const int tt = k - j;
                    if (tt >= 0 && tt < WS) {
                        const float g = P.g[tt];
                        Asd[j] += g * bsd[k-7];
                        Ae2[j] += g * be2[k-7];
                    }
                }
            }
        }
        const int ox = ox0 + cc;
#pragma unroll
        for (int j = 0; j < 4; ++j) {
            const int oy = oy0 + t*32 + r0c + j;
            if (oy < OH && ox < OH) {     // OW == OH (square)
                const float ms = Asd[j].x, md = Asd[j].y;
                const float Es = Ae2[j].x, Ed = Ae2[j].y;
                const float ms2 = ms*ms, md2 = md*md;
                const float mu12 = 0.25f * (ms2 - md2);
                const float musq = 0.5f  * (ms2 + md2);             // mu1^2+mu2^2
                const float v1 = 0.5f * (Es - Ed) - 2.f*mu12 + C2V; // 2*sig12+C2
                const float v2 = 0.5f * (Es + Ed) - musq + C2V;     // sig1+sig2+C2
                const float rv2 = __builtin_amdgcn_rcpf(v2);
                const float cs  = v1 * rv2;
                const float ssim = (2.f*mu12 + C1V) *
                                   __builtin_amdgcn_rcpf(musq + C1V) * cs;
                ssim_acc += ssim;
                cs_acc   += cs;
            }
        }

        // ---- fused 2x2 avg pool of this chunk's 32x32 core (1 out/thread) ----
        if (POOL) {
            const int px = tid & 15, py = tid >> 4;
            const int yy = oy0 + t*32 + 2*py;
            const int xx = ox0 + 2*px;
            const float2 a0 = *(const float2*)(p1 + (size_t)yy*H + xx);
            const float2 a1 = *(const float2*)(p1 + (size_t)(yy+1)*H + xx);
            const float2 b0 = *(const float2*)(p2 + (size_t)yy*H + xx);
            const float2 b1 = *(const float2*)(p2 + (size_t)(yy+1)*H + xx);
            const int h = H >> 1;
            const size_t ob = (size_t)img*h*h +
                              (size_t)(((oy0 + t*32) >> 1) + py)*h + (ox0 >> 1) + px;
            pool1[ob] = 0.25f * (a0.x + a0.y + a1.x + a1.y);
            pool2[ob] = 0.25f * (b0.x + b0.y + b1.x + b1.y);
        }

        // ---- carry: slots 32..41 -> slots 0..9 (10 rows x 32 cols, 2 planes)
        if (t + 1 < CH) {
            __syncthreads();              // col-conv reads of slots 0..9 done
            for (int u = tid; u < 320; u += 256) {
                const int r = u >> 5, c = u & 31;
                rpSD[r][c] = rpSD[32 + r][c];
                rpE2[r][c] = rpE2[32 + r][c];
            }
            __syncthreads();              // carry done before next row-conv
        }
    }

    // ---- deterministic block reduction -> one partial per block ----
#pragma unroll
    for (int off = 32; off > 0; off >>= 1) {
        ssim_acc += __shfl_down(ssim_acc, off);
        cs_acc   += __shfl_down(cs_acc, off);
    }
    const int wave = tid >> 6, lane = tid & 63;
    if (lane == 0) { reds[wave] = ssim_acc; redc[wave] = cs_acc; }
    __syncthreads();
    if (tid == 0) {
        const float s   = reds[0] + reds[1] + reds[2] + reds[3];
        const float cc2 = redc[0] + redc[1] + redc[2] + redc[3];
        partial[(size_t)partial_off + (size_t)blockIdx.y * gridDim.x + blockIdx.x] =
            make_float2(s, cc2);
    }
}

// ---------------- single fused reduce over all levels + final product ----------------
__global__ __launch_bounds__(256) void reduce_final_kernel(
    const float2* __restrict__ partial, ROff ro, float* __restrict__ out)
{
    __shared__ float sS[5], sC[5];
    __shared__ float reds[4], redc[4];
    const int tid = threadIdx.x;
    for (int l = 0; l < 5; ++l) {
        float s = 0.f, c = 0.f;
        for (int i = tid; i < ro.cnt[l]; i += 256) {
            const float2 v = partial[ro.off[l] + i];
            s += v.x; c += v.y;
        }
#pragma unroll
        for (int off = 32; off > 0; off >>= 1) {
            s += __shfl_down(s, off);
            c += __shfl_down(c, off);
        }
        const int wave = tid >> 6, lane = tid & 63;
        if (lane == 0) { reds[wave] = s; redc[wave] = c; }
        __syncthreads();
        if (tid == 0) {
            sS[l] = (reds[0] + reds[1] + reds[2] + reds[3]) * ro.inv[l];
            sC[l] = (redc[0] + redc[1] + redc[2] + redc[3]) * ro.inv[l];
        }
        __syncthreads();
    }
    if (tid == 0) {
        const float w[5] = {0.0448f, 0.2856f, 0.3001f, 0.2363f, 0.1333f};
        float prod = 1.f;
#pragma unroll
        for (int i = 0; i < 4; ++i)
            prod *= powf((sC[i] + 1.f) * 0.5f, w[i]);
        prod *= powf((sS[4] + 1.f) * 0.5f, w[4]);
        out[0] = prod;
    }
}

// ---------------- host launch ----------------
extern "C" void kernel_launch(void* const* d_in, const int* in_sizes, int n_in,
                              void* d_out, int out_size, void* d_ws, size_t ws_size,
                              hipStream_t stream)
{
    const float* img1 = (const float*)d_in[0];
    const float* img2 = (const float*)d_in[1];
    float* out = (float*)d_out;
    float* ws  = (float*)d_ws;

    // Gaussian window (sigma = 1.5), normalized
    Params P;
    {
        double g[WS], sum = 0.0;
        for (int i = 0; i < WS; ++i) {
            double x = (double)i - (WS / 2);
            g[i] = exp(-x * x / (2.0 * 1.5 * 1.5));
            sum += g[i];
        }
        for (int i = 0; i < WS; ++i) P.g[i] = (float)(g[i] / sum);
    }

    // workspace layout: pyramid levels 1..4 (both images), then partials
    float* p1[5]; float* p2[5];
    p1[0] = (float*)img1; p2[0] = (float*)img2;
    size_t o = 0;
    for (int l = 1; l < 5; ++l) {
        const int H = 512 >> l;
        p1[l] = ws + o; o += (size_t)NC * H * H;
        p2[l] = ws + o; o += (size_t)NC * H * H;
    }
    float2* partial = (float2*)(ws + o);
    (void)ws_size; (void)in_sizes; (void)n_in; (void)out_size;

    const int CHv[5] = {4, 2, 1, 1, 1};   // chunks per strip, per level
    ROff ro;
    {
        int off = 0;
        for (int l = 0; l < 5; ++l) {
            const int H = 512 >> l, OH = H - PAD;
            const int tilesX = (OH + 31) / 32;
            const int tilesY = (OH + CHv[l]*32 - 1) / (CHv[l]*32);
            ro.off[l] = off;
            ro.cnt[l] = tilesX * tilesY * NC;
            ro.inv[l] = 1.f / ((float)NC * OH * OH);
            off += ro.cnt[l];
        }
    }

    for (int l = 0; l < 5; ++l) {
        const int H = 512 >> l, OH = H - PAD;
        const int tilesX = (OH + 31) / 32;
        const int tilesY = (OH + CHv[l]*32 - 1) / (CHv[l]*32);
        const dim3 grid(tilesX * tilesY, NC);
        switch (l) {
        case 0:
            ssim_strip_kernel<4,1><<<grid, 256, 0, stream>>>(
                p1[0], p2[0], p1[1], p2[1], H, OH, tilesX, P, partial, ro.off[0]);
            break;
        case 1:
            ssim_strip_kernel<2,1><<<grid, 256, 0, stream>>>(
                p1[1], p2[1], p1[2], p2[2], H, OH, tilesX, P, partial, ro.off[1]);
            break;
        case 2:
            ssim_strip_kernel<1,1><<<grid, 256, 0, stream>>>(
                p1[2], p2[2], p1[3], p2[3], H, OH, tilesX, P, partial, ro.off[2]);
            break;
        case 3:
            ssim_strip_kernel<1,1><<<grid, 256, 0, stream>>>(
                p1[3], p2[3], p1[4], p2[4], H, OH, tilesX, P, partial, ro.off[3]);
            break;
        default:
            ssim_strip_kernel<1,0><<<grid, 256, 0, stream>>>(
                p1[4], p2[4], nullptr, nullptr, H, OH, tilesX, P, partial, ro.off[4]);
            break;
        }
    }

    reduce_final_kernel<<<1, 256, 0, stream>>>(partial, ro, out);
}